// Round 1
// baseline (2477.239 us; speedup 1.0000x reference)
//
#include <hip/hip_runtime.h>

#define T_TOK 4096
#define HD    1024
#define FFD   2048
#define NE    8
#define TT    32      // tokens per tile
#define KC    64      // k chunk staged in LDS
#define FC    512     // ff chunk
#define NTH   512

// ---------------- gating + routing ----------------
__global__ __launch_bounds__(256) void gate_route_kernel(
    const float* __restrict__ x, const float* __restrict__ Wg,
    const float* __restrict__ bg,
    int* __restrict__ counts, int* __restrict__ ids, float* __restrict__ wts)
{
  int wave = threadIdx.x >> 6;
  int lane = threadIdx.x & 63;
  int t = blockIdx.x * 4 + wave;
  if (t >= T_TOK) return;

  float acc[NE];
#pragma unroll
  for (int e = 0; e < NE; ++e) acc[e] = 0.f;

  const float* xr = x + (size_t)t * HD;
  for (int h = lane; h < HD; h += 64) {
    float xv = xr[h];
    float4 a = *(const float4*)(Wg + (size_t)h * NE);
    float4 b = *(const float4*)(Wg + (size_t)h * NE + 4);
    acc[0] = fmaf(xv, a.x, acc[0]); acc[1] = fmaf(xv, a.y, acc[1]);
    acc[2] = fmaf(xv, a.z, acc[2]); acc[3] = fmaf(xv, a.w, acc[3]);
    acc[4] = fmaf(xv, b.x, acc[4]); acc[5] = fmaf(xv, b.y, acc[5]);
    acc[6] = fmaf(xv, b.z, acc[6]); acc[7] = fmaf(xv, b.w, acc[7]);
  }
#pragma unroll
  for (int off = 32; off > 0; off >>= 1) {
#pragma unroll
    for (int e = 0; e < NE; ++e) acc[e] += __shfl_xor(acc[e], off);
  }
  if (lane == 0) {
    float lg[NE];
#pragma unroll
    for (int e = 0; e < NE; ++e) lg[e] = acc[e] + bg[e];
    // top-2 by value, ties -> lower index (matches lax.top_k)
    int i1 = 0;
#pragma unroll
    for (int e = 1; e < NE; ++e) if (lg[e] > lg[i1]) i1 = e;
    int i2 = (i1 == 0) ? 1 : 0;
#pragma unroll
    for (int e = 0; e < NE; ++e) if (e != i1 && lg[e] > lg[i2]) i2 = e;
    // renormalized top-2 of softmax == pairwise softmax of top-2 logits
    float p2 = expf(lg[i2] - lg[i1]);
    float s  = 1.f + p2;
    float w1 = 1.f / s;
    float w2 = p2 / s;
    int s1 = atomicAdd(&counts[i1], 1);
    ids[i1 * T_TOK + s1] = t; wts[i1 * T_TOK + s1] = w1;
    int s2 = atomicAdd(&counts[i2], 1);
    ids[i2 * T_TOK + s2] = t; wts[i2 * T_TOK + s2] = w2;
  }
}

// ---------------- fused expert MLP (fp32) ----------------
// block = (expert, 32-token tile), 512 threads.
// GEMM1: h = relu(x_tile @ W1[e] + b1[e]) computed FC columns at a time,
//        x k-chunk staged transposed in LDS (broadcast b128 reads).
// GEMM2: out_acc += h_chunk @ W2[e] with h kept transposed in LDS.
__global__ __launch_bounds__(NTH, 1) void moe_mlp_kernel(
    const float* __restrict__ x,
    const float* __restrict__ W1, const float* __restrict__ b1,
    const float* __restrict__ W2, const float* __restrict__ b2,
    const int* __restrict__ counts, const int* __restrict__ ids,
    const float* __restrict__ wts, float* __restrict__ out)
{
  const int e   = blockIdx.y;
  const int cnt = counts[e];
  const int t0  = blockIdx.x * TT;
  if (t0 >= cnt) return;

  __shared__ float xs[KC][TT + 4];   // 64 x 36 x 4B = 9.2 KB (row = 144B, 16B aligned)
  __shared__ float hs[FC][TT + 4];   // 512 x 36 x 4B = 73.7 KB
  __shared__ int   rows[TT];
  __shared__ float tww[TT];

  const int tid = threadIdx.x;
  if (tid < TT) {
    int idx = t0 + tid;
    if (idx < cnt) { rows[tid] = ids[e * T_TOK + idx]; tww[tid] = wts[e * T_TOK + idx]; }
    else           { rows[tid] = -1;                   tww[tid] = 0.f; }
  }

  // stage-B accumulator: thread owns output columns c0, c0+1 (c0 = 2*tid)
  float accB[TT][2];
#pragma unroll
  for (int t = 0; t < TT; ++t) { accB[t][0] = 0.f; accB[t][1] = 0.f; }

  for (int fc = 0; fc < FFD; fc += FC) {
    // ---- stage A: accA[t] = sum_k x[t][k] * W1[e][k][fc + tid]
    float accA[TT];
#pragma unroll
    for (int t = 0; t < TT; ++t) accA[t] = 0.f;

    for (int kc = 0; kc < HD; kc += KC) {
      __syncthreads();
      {
        // stage xs transposed: 2048 elems, 1 float4 per thread along k
        int t  = tid >> 4;            // 0..31
        int kk = (tid & 15) << 2;     // 0,4,...,60
        int row = rows[t];
        float4 v = make_float4(0.f, 0.f, 0.f, 0.f);
        if (row >= 0) v = *(const float4*)(x + (size_t)row * HD + kc + kk);
        xs[kk + 0][t] = v.x; xs[kk + 1][t] = v.y;
        xs[kk + 2][t] = v.z; xs[kk + 3][t] = v.w;
      }
      __syncthreads();
      const float* w1p = W1 + ((size_t)e * HD + kc) * FFD + fc + tid;
#pragma unroll 4
      for (int kk = 0; kk < KC; ++kk) {
        float wv = w1p[(size_t)kk * FFD];
#pragma unroll
        for (int t4 = 0; t4 < TT / 4; ++t4) {
          float4 xv = *(const float4*)&xs[kk][t4 * 4];
          accA[t4 * 4 + 0] = fmaf(xv.x, wv, accA[t4 * 4 + 0]);
          accA[t4 * 4 + 1] = fmaf(xv.y, wv, accA[t4 * 4 + 1]);
          accA[t4 * 4 + 2] = fmaf(xv.z, wv, accA[t4 * 4 + 2]);
          accA[t4 * 4 + 3] = fmaf(xv.w, wv, accA[t4 * 4 + 3]);
        }
      }
    }
    // write h chunk (relu + b1), transposed
    {
      float b1v = b1[e * FFD + fc + tid];
#pragma unroll
      for (int t = 0; t < TT; ++t)
        hs[tid][t] = fmaxf(accA[t] + b1v, 0.f);
    }
    __syncthreads();
    // ---- stage B: accB[t][c] += hs[f][t] * W2[e][fc+f][c]
    const float* w2p = W2 + ((size_t)e * FFD + fc) * HD + 2 * tid;
#pragma unroll 2
    for (int f = 0; f < FC; ++f) {
      float2 wv = *(const float2*)(w2p + (size_t)f * HD);
#pragma unroll
      for (int t4 = 0; t4 < TT / 4; ++t4) {
        float4 hv = *(const float4*)&hs[f][t4 * 4];
        accB[t4*4+0][0] = fmaf(hv.x, wv.x, accB[t4*4+0][0]);
        accB[t4*4+0][1] = fmaf(hv.x, wv.y, accB[t4*4+0][1]);
        accB[t4*4+1][0] = fmaf(hv.y, wv.x, accB[t4*4+1][0]);
        accB[t4*4+1][1] = fmaf(hv.y, wv.y, accB[t4*4+1][1]);
        accB[t4*4+2][0] = fmaf(hv.z, wv.x, accB[t4*4+2][0]);
        accB[t4*4+2][1] = fmaf(hv.z, wv.y, accB[t4*4+2][1]);
        accB[t4*4+3][0] = fmaf(hv.w, wv.x, accB[t4*4+3][0]);
        accB[t4*4+3][1] = fmaf(hv.w, wv.y, accB[t4*4+3][1]);
      }
    }
    // hs is only overwritten after next fc's kc-loop barriers, safe.
  }

  // ---- epilogue: out[row] += w * (accB + b2)
  const int c0 = 2 * tid;
  float b2v0 = b2[e * HD + c0];
  float b2v1 = b2[e * HD + c0 + 1];
#pragma unroll
  for (int t = 0; t < TT; ++t) {
    int row = rows[t];
    if (row < 0) continue;
    float w = tww[t];
    float* op = out + (size_t)row * HD + c0;
    atomicAdd(op + 0, w * (accB[t][0] + b2v0));
    atomicAdd(op + 1, w * (accB[t][1] + b2v1));
  }
}

extern "C" void kernel_launch(void* const* d_in, const int* in_sizes, int n_in,
                              void* d_out, int out_size, void* d_ws, size_t ws_size,
                              hipStream_t stream) {
  const float* x  = (const float*)d_in[0];
  const float* Wg = (const float*)d_in[1];
  const float* bg = (const float*)d_in[2];
  const float* W1 = (const float*)d_in[3];
  const float* b1 = (const float*)d_in[4];
  const float* W2 = (const float*)d_in[5];
  const float* b2 = (const float*)d_in[6];
  float* out = (float*)d_out;

  // ws layout: [counts: 64 ints][ids: 8*4096 ints][wts: 8*4096 floats]
  int*   counts = (int*)d_ws;
  int*   ids    = (int*)((char*)d_ws + 256);
  float* wts    = (float*)((char*)d_ws + 256 + (size_t)T_TOK * NE * 4);

  hipMemsetAsync(counts, 0, 256, stream);
  hipMemsetAsync(d_out, 0, (size_t)out_size * sizeof(float), stream);

  gate_route_kernel<<<T_TOK / 4, 256, 0, stream>>>(x, Wg, bg, counts, ids, wts);

  dim3 grid(T_TOK / TT, NE);
  moe_mlp_kernel<<<grid, NTH, 0, stream>>>(x, W1, b1, W2, b2,
                                           counts, ids, wts, out);
}

// Round 2
// 649.294 us; speedup vs baseline: 3.8153x; 3.8153x over previous
//
#include <hip/hip_runtime.h>
#include <hip/hip_bf16.h>

#define T_TOK 4096
#define HD    1024
#define FFD   2048
#define NE    8
#define TT    32      // tokens per MFMA tile
#define FC    512     // ff chunk per iteration
#define NTH   512

typedef __attribute__((ext_vector_type(8))) short short8;
typedef __attribute__((ext_vector_type(4))) float f32x4;

__device__ inline unsigned short f2bf(float f) {
  __hip_bfloat16 h = __float2bfloat16(f);
  return __builtin_bit_cast(unsigned short, h);
}

// ---------------- gating + routing ----------------
__global__ __launch_bounds__(256) void gate_route_kernel(
    const float* __restrict__ x, const float* __restrict__ Wg,
    const float* __restrict__ bg,
    int* __restrict__ counts, int* __restrict__ ids, float* __restrict__ wts)
{
  int wave = threadIdx.x >> 6;
  int lane = threadIdx.x & 63;
  int t = blockIdx.x * 4 + wave;
  if (t >= T_TOK) return;

  float acc[NE];
#pragma unroll
  for (int e = 0; e < NE; ++e) acc[e] = 0.f;

  const float* xr = x + (size_t)t * HD;
  for (int h = lane; h < HD; h += 64) {
    float xv = xr[h];
    float4 a = *(const float4*)(Wg + (size_t)h * NE);
    float4 b = *(const float4*)(Wg + (size_t)h * NE + 4);
    acc[0] = fmaf(xv, a.x, acc[0]); acc[1] = fmaf(xv, a.y, acc[1]);
    acc[2] = fmaf(xv, a.z, acc[2]); acc[3] = fmaf(xv, a.w, acc[3]);
    acc[4] = fmaf(xv, b.x, acc[4]); acc[5] = fmaf(xv, b.y, acc[5]);
    acc[6] = fmaf(xv, b.z, acc[6]); acc[7] = fmaf(xv, b.w, acc[7]);
  }
#pragma unroll
  for (int off = 32; off > 0; off >>= 1) {
#pragma unroll
    for (int e = 0; e < NE; ++e) acc[e] += __shfl_xor(acc[e], off);
  }
  if (lane == 0) {
    float lg[NE];
#pragma unroll
    for (int e = 0; e < NE; ++e) lg[e] = acc[e] + bg[e];
    int i1 = 0;
#pragma unroll
    for (int e = 1; e < NE; ++e) if (lg[e] > lg[i1]) i1 = e;
    int i2 = (i1 == 0) ? 1 : 0;
#pragma unroll
    for (int e = 0; e < NE; ++e) if (e != i1 && lg[e] > lg[i2]) i2 = e;
    float p2 = expf(lg[i2] - lg[i1]);
    float s  = 1.f + p2;
    float w1 = 1.f / s;
    float w2 = p2 / s;
    int s1 = atomicAdd(&counts[i1], 1);
    ids[i1 * T_TOK + s1] = t; wts[i1 * T_TOK + s1] = w1;
    int s2 = atomicAdd(&counts[i2], 1);
    ids[i2 * T_TOK + s2] = t; wts[i2 * T_TOK + s2] = w2;
  }
}

// ---------------- weight transpose + bf16 convert ----------------
// in: [E][R][C] fp32 -> out: [E][C][R] bf16
__global__ __launch_bounds__(256) void transpose_cvt_kernel(
    const float* __restrict__ in, unsigned short* __restrict__ out,
    int R, int C)
{
  __shared__ float tile[64][69];
  const int z  = blockIdx.z;
  const int r0 = blockIdx.y * 64, c0 = blockIdx.x * 64;
  const int t  = threadIdx.x;
  const float* ip = in + ((size_t)z * R + r0) * C + c0;
  int tr = t >> 4, tc = (t & 15) * 4;
#pragma unroll
  for (int j = 0; j < 4; ++j) {
    float4 v = *(const float4*)(ip + (size_t)(tr + j * 16) * C + tc);
    float* tp = &tile[tr + j * 16][tc];
    tp[0] = v.x; tp[1] = v.y; tp[2] = v.z; tp[3] = v.w;
  }
  __syncthreads();
  unsigned short* op = out + ((size_t)z * C + c0) * R + r0;
  int oc = t >> 4, orr = (t & 15) * 4;
#pragma unroll
  for (int j = 0; j < 4; ++j) {
    int c = oc + j * 16;
    ushort4 w;
    w.x = f2bf(tile[orr + 0][c]);
    w.y = f2bf(tile[orr + 1][c]);
    w.z = f2bf(tile[orr + 2][c]);
    w.w = f2bf(tile[orr + 3][c]);
    *(ushort4*)(op + (size_t)c * R + orr) = w;
  }
}

// ---------------- fused expert MLP, bf16 MFMA ----------------
// block = 8 waves; expert = bid&7 (XCD-pinned), token tile = bid>>3.
// GEMM1: h[32 x FC] = relu(x@W1+b1) per chunk (wave owns 64 h-cols)
// GEMM2: acc[32 x 1024] += h@W2 (wave owns 128 out-cols)
__global__ __launch_bounds__(NTH, 2) void moe_mlp_mfma_kernel(
    const float* __restrict__ x,
    const unsigned short* __restrict__ W1T,  // [E][FFD][HD] bf16
    const unsigned short* __restrict__ W2T,  // [E][HD][FFD] bf16
    const float* __restrict__ b1, const float* __restrict__ b2,
    const int* __restrict__ counts, const int* __restrict__ ids,
    const float* __restrict__ wts, float* __restrict__ out)
{
  const int bid  = blockIdx.x;
  const int e    = bid & 7;
  const int tile = bid >> 3;
  const int cnt  = counts[e];
  const int t0   = tile * TT;
  if (t0 >= cnt) return;

  __shared__ unsigned short xs[TT * HD];  // 64 KB, XOR-swizzled 16B chunks
  __shared__ unsigned short hs[TT * FC];  // 32 KB, XOR-swizzled
  __shared__ int   rows[TT];
  __shared__ float tww[TT];

  const int tid  = threadIdx.x;
  const int w    = tid >> 6;
  const int lane = tid & 63;
  const int g    = lane >> 4;   // K-group 0..3
  const int rA   = lane & 15;   // M/N index within frag

  if (tid < TT) {
    int idx = t0 + tid;
    rows[tid] = (idx < cnt) ? ids[e * T_TOK + idx] : -1;
    tww[tid]  = (idx < cnt) ? wts[e * T_TOK + idx] : 0.f;
  }
  __syncthreads();

  // ---- stage x tile (gather rows, fp32 -> bf16, swizzled) ----
#pragma unroll
  for (int it = 0; it < 8; ++it) {
    int c   = it * NTH + tid;       // 16B-chunk id: 0..4095
    int row = c >> 7;               // 0..31
    int ck  = c & 127;              // chunk within row
    int sck = ck ^ (row & 7);
    short8 sv;
    int rsrc = rows[row];
    if (rsrc >= 0) {
      const float* xp = x + (size_t)rsrc * HD + ck * 8;
      float4 lo = *(const float4*)xp;
      float4 hi = *(const float4*)(xp + 4);
      sv[0] = (short)f2bf(lo.x); sv[1] = (short)f2bf(lo.y);
      sv[2] = (short)f2bf(lo.z); sv[3] = (short)f2bf(lo.w);
      sv[4] = (short)f2bf(hi.x); sv[5] = (short)f2bf(hi.y);
      sv[6] = (short)f2bf(hi.z); sv[7] = (short)f2bf(hi.w);
    } else {
      sv = (short8)0;
    }
    *(short8*)&xs[row * HD + (sck << 3)] = sv;
  }
  __syncthreads();

  f32x4 acc2[2][8];
#pragma unroll
  for (int mf = 0; mf < 2; ++mf)
#pragma unroll
    for (int nf = 0; nf < 8; ++nf)
      acc2[mf][nf] = (f32x4){0.f, 0.f, 0.f, 0.f};

  const unsigned short* W1e = W1T + (size_t)e * FFD * HD;
  const unsigned short* W2e = W2T + (size_t)e * HD * FFD;
  const int sw = rA & 7;

  for (int fc = 0; fc < FFD; fc += FC) {
    // ---- GEMM1: acc1[2][4] = x_tile @ W1T-rows (wave cols fc+w*64..+64)
    f32x4 acc1[2][4];
#pragma unroll
    for (int mf = 0; mf < 2; ++mf)
#pragma unroll
      for (int nf = 0; nf < 4; ++nf)
        acc1[mf][nf] = (f32x4){0.f, 0.f, 0.f, 0.f};

    const unsigned short* bbase = W1e + (size_t)(fc + w * 64 + rA) * HD + 8 * g;
    for (int k0 = 0; k0 < HD; k0 += 32) {
      int ckA = (k0 >> 3) + g;
      int sa  = ((ckA ^ sw) << 3);
      short8 a0 = *(const short8*)&xs[rA * HD + sa];
      short8 a1 = *(const short8*)&xs[(16 + rA) * HD + sa];
      short8 b0 = *(const short8*)(bbase + k0);
      short8 b1f = *(const short8*)(bbase + 16 * HD + k0);
      short8 b2f = *(const short8*)(bbase + 32 * HD + k0);
      short8 b3f = *(const short8*)(bbase + 48 * HD + k0);
      acc1[0][0] = __builtin_amdgcn_mfma_f32_16x16x32_bf16(a0, b0,  acc1[0][0], 0, 0, 0);
      acc1[1][0] = __builtin_amdgcn_mfma_f32_16x16x32_bf16(a1, b0,  acc1[1][0], 0, 0, 0);
      acc1[0][1] = __builtin_amdgcn_mfma_f32_16x16x32_bf16(a0, b1f, acc1[0][1], 0, 0, 0);
      acc1[1][1] = __builtin_amdgcn_mfma_f32_16x16x32_bf16(a1, b1f, acc1[1][1], 0, 0, 0);
      acc1[0][2] = __builtin_amdgcn_mfma_f32_16x16x32_bf16(a0, b2f, acc1[0][2], 0, 0, 0);
      acc1[1][2] = __builtin_amdgcn_mfma_f32_16x16x32_bf16(a1, b2f, acc1[1][2], 0, 0, 0);
      acc1[0][3] = __builtin_amdgcn_mfma_f32_16x16x32_bf16(a0, b3f, acc1[0][3], 0, 0, 0);
      acc1[1][3] = __builtin_amdgcn_mfma_f32_16x16x32_bf16(a1, b3f, acc1[1][3], 0, 0, 0);
    }

    __syncthreads();  // prev chunk's GEMM2 done reading hs
    // ---- write h chunk: relu(acc1 + b1) -> hs (bf16, swizzled)
    float b1v[4];
#pragma unroll
    for (int nf = 0; nf < 4; ++nf)
      b1v[nf] = b1[e * FFD + fc + w * 64 + nf * 16 + rA];
#pragma unroll
    for (int mf = 0; mf < 2; ++mf)
#pragma unroll
      for (int nf = 0; nf < 4; ++nf)
#pragma unroll
        for (int r = 0; r < 4; ++r) {
          int row = mf * 16 + g * 4 + r;
          int col = w * 64 + nf * 16 + rA;
          float hv = fmaxf(acc1[mf][nf][r] + b1v[nf], 0.f);
          int ck = col >> 3;
          hs[row * FC + ((ck ^ (row & 7)) << 3) + (col & 7)] = f2bf(hv);
        }
    __syncthreads();

    // ---- GEMM2: acc2 += h_chunk @ W2T-rows (wave cols w*128..+128)
    const unsigned short* b2base = W2e + (size_t)(w * 128 + rA) * FFD + fc + 8 * g;
    for (int k0 = 0; k0 < FC; k0 += 32) {
      int ckA = (k0 >> 3) + g;
      int sa  = ((ckA ^ sw) << 3);
      short8 a0 = *(const short8*)&hs[rA * FC + sa];
      short8 a1 = *(const short8*)&hs[(16 + rA) * FC + sa];
#pragma unroll
      for (int nf = 0; nf < 8; ++nf) {
        short8 bv = *(const short8*)(b2base + (size_t)nf * 16 * FFD + k0);
        acc2[0][nf] = __builtin_amdgcn_mfma_f32_16x16x32_bf16(a0, bv, acc2[0][nf], 0, 0, 0);
        acc2[1][nf] = __builtin_amdgcn_mfma_f32_16x16x32_bf16(a1, bv, acc2[1][nf], 0, 0, 0);
      }
    }
  }

  // ---- epilogue: out[row] += w_t * (acc2 + b2)
#pragma unroll
  for (int mf = 0; mf < 2; ++mf)
#pragma unroll
    for (int nf = 0; nf < 8; ++nf) {
      int col = w * 128 + nf * 16 + rA;
      float b2v = b2[e * HD + col];
#pragma unroll
      for (int r = 0; r < 4; ++r) {
        int row = mf * 16 + g * 4 + r;
        int tr = rows[row];
        if (tr < 0) continue;
        atomicAdd(&out[(size_t)tr * HD + col], tww[row] * (acc2[mf][nf][r] + b2v));
      }
    }
}

// ---------------- fallback fp32 MLP (round-1 kernel) ----------------
#define FTT 32
#define FKC 64
#define FFC 512
__global__ __launch_bounds__(512, 1) void moe_mlp_kernel(
    const float* __restrict__ x,
    const float* __restrict__ W1, const float* __restrict__ b1,
    const float* __restrict__ W2, const float* __restrict__ b2,
    const int* __restrict__ counts, const int* __restrict__ ids,
    const float* __restrict__ wts, float* __restrict__ out)
{
  const int e   = blockIdx.y;
  const int cnt = counts[e];
  const int t0  = blockIdx.x * FTT;
  if (t0 >= cnt) return;

  __shared__ float xs[FKC][FTT + 4];
  __shared__ float hs[FFC][FTT + 4];
  __shared__ int   rows[FTT];
  __shared__ float tww[FTT];

  const int tid = threadIdx.x;
  if (tid < FTT) {
    int idx = t0 + tid;
    if (idx < cnt) { rows[tid] = ids[e * T_TOK + idx]; tww[tid] = wts[e * T_TOK + idx]; }
    else           { rows[tid] = -1;                   tww[tid] = 0.f; }
  }
  float accB[FTT][2];
#pragma unroll
  for (int t = 0; t < FTT; ++t) { accB[t][0] = 0.f; accB[t][1] = 0.f; }

  for (int fcc = 0; fcc < FFD; fcc += FFC) {
    float accA[FTT];
#pragma unroll
    for (int t = 0; t < FTT; ++t) accA[t] = 0.f;
    for (int kc = 0; kc < HD; kc += FKC) {
      __syncthreads();
      {
        int t  = tid >> 4;
        int kk = (tid & 15) << 2;
        int row = rows[t];
        float4 v = make_float4(0.f, 0.f, 0.f, 0.f);
        if (row >= 0) v = *(const float4*)(x + (size_t)row * HD + kc + kk);
        xs[kk + 0][t] = v.x; xs[kk + 1][t] = v.y;
        xs[kk + 2][t] = v.z; xs[kk + 3][t] = v.w;
      }
      __syncthreads();
      const float* w1p = W1 + ((size_t)e * HD + kc) * FFD + fcc + tid;
#pragma unroll 4
      for (int kk = 0; kk < FKC; ++kk) {
        float wv = w1p[(size_t)kk * FFD];
#pragma unroll
        for (int t4 = 0; t4 < FTT / 4; ++t4) {
          float4 xv = *(const float4*)&xs[kk][t4 * 4];
          accA[t4 * 4 + 0] = fmaf(xv.x, wv, accA[t4 * 4 + 0]);
          accA[t4 * 4 + 1] = fmaf(xv.y, wv, accA[t4 * 4 + 1]);
          accA[t4 * 4 + 2] = fmaf(xv.z, wv, accA[t4 * 4 + 2]);
          accA[t4 * 4 + 3] = fmaf(xv.w, wv, accA[t4 * 4 + 3]);
        }
      }
    }
    {
      float b1v = b1[e * FFD + fcc + tid];
#pragma unroll
      for (int t = 0; t < FTT; ++t)
        hs[tid][t] = fmaxf(accA[t] + b1v, 0.f);
    }
    __syncthreads();
    const float* w2p = W2 + ((size_t)e * FFD + fcc) * HD + 2 * tid;
#pragma unroll 2
    for (int f = 0; f < FFC; ++f) {
      float2 wv = *(const float2*)(w2p + (size_t)f * HD);
#pragma unroll
      for (int t4 = 0; t4 < FTT / 4; ++t4) {
        float4 hv = *(const float4*)&hs[f][t4 * 4];
        accB[t4*4+0][0] = fmaf(hv.x, wv.x, accB[t4*4+0][0]);
        accB[t4*4+0][1] = fmaf(hv.x, wv.y, accB[t4*4+0][1]);
        accB[t4*4+1][0] = fmaf(hv.y, wv.x, accB[t4*4+1][0]);
        accB[t4*4+1][1] = fmaf(hv.y, wv.y, accB[t4*4+1][1]);
        accB[t4*4+2][0] = fmaf(hv.z, wv.x, accB[t4*4+2][0]);
        accB[t4*4+2][1] = fmaf(hv.z, wv.y, accB[t4*4+2][1]);
        accB[t4*4+3][0] = fmaf(hv.w, wv.x, accB[t4*4+3][0]);
        accB[t4*4+3][1] = fmaf(hv.w, wv.y, accB[t4*4+3][1]);
      }
    }
  }
  const int c0 = 2 * tid;
  float b2v0 = b2[e * HD + c0];
  float b2v1 = b2[e * HD + c0 + 1];
#pragma unroll
  for (int t = 0; t < FTT; ++t) {
    int row = rows[t];
    if (row < 0) continue;
    float w = tww[t];
    float* op = out + (size_t)row * HD + c0;
    atomicAdd(op + 0, w * (accB[t][0] + b2v0));
    atomicAdd(op + 1, w * (accB[t][1] + b2v1));
  }
}

extern "C" void kernel_launch(void* const* d_in, const int* in_sizes, int n_in,
                              void* d_out, int out_size, void* d_ws, size_t ws_size,
                              hipStream_t stream) {
  const float* x  = (const float*)d_in[0];
  const float* Wg = (const float*)d_in[1];
  const float* bg = (const float*)d_in[2];
  const float* W1 = (const float*)d_in[3];
  const float* b1 = (const float*)d_in[4];
  const float* W2 = (const float*)d_in[5];
  const float* b2 = (const float*)d_in[6];
  float* out = (float*)d_out;

  // ws layout: [counts 1KB][ids 128KB][wts 128KB][W1T 32MB][W2T 32MB]
  const size_t OFF_IDS = 1024;
  const size_t OFF_WTS = OFF_IDS + (size_t)T_TOK * NE * 4;
  const size_t OFF_W1T = OFF_WTS + (size_t)T_TOK * NE * 4;         // 263168, 256-aligned
  const size_t OFF_W2T = OFF_W1T + (size_t)NE * HD * FFD * 2;
  const size_t REQ     = OFF_W2T + (size_t)NE * HD * FFD * 2;      // ~64.3 MB

  int*   counts = (int*)d_ws;
  int*   ids    = (int*)((char*)d_ws + OFF_IDS);
  float* wts    = (float*)((char*)d_ws + OFF_WTS);

  hipMemsetAsync(counts, 0, 1024, stream);
  hipMemsetAsync(d_out, 0, (size_t)out_size * sizeof(float), stream);

  gate_route_kernel<<<T_TOK / 4, 256, 0, stream>>>(x, Wg, bg, counts, ids, wts);

  if (ws_size >= REQ) {
    unsigned short* W1T = (unsigned short*)((char*)d_ws + OFF_W1T);
    unsigned short* W2T = (unsigned short*)((char*)d_ws + OFF_W2T);
    transpose_cvt_kernel<<<dim3(FFD / 64, HD / 64, NE), 256, 0, stream>>>(W1, W1T, HD, FFD);
    transpose_cvt_kernel<<<dim3(HD / 64, FFD / 64, NE), 256, 0, stream>>>(W2, W2T, FFD, HD);
    moe_mlp_mfma_kernel<<<(T_TOK / TT) * NE, NTH, 0, stream>>>(
        x, W1T, W2T, b1, b2, counts, ids, wts, out);
  } else {
    dim3 grid(T_TOK / FTT, NE);
    moe_mlp_kernel<<<grid, 512, 0, stream>>>(x, W1, b1, W2, b2,
                                             counts, ids, wts, out);
  }
}

// Round 3
// 381.653 us; speedup vs baseline: 6.4908x; 1.7013x over previous
//
#include <hip/hip_runtime.h>
#include <hip/hip_bf16.h>

#define T_TOK 4096
#define HD    1024
#define FFD   2048
#define NE    8
#define NTH_F 512

typedef __attribute__((ext_vector_type(8))) short short8;
typedef __attribute__((ext_vector_type(4))) float f32x4;

__device__ __forceinline__ unsigned short f2bf(float f) {
  __hip_bfloat16 h = __float2bfloat16(f);
  return __builtin_bit_cast(unsigned short, h);
}

__device__ __forceinline__ void gload_lds16(const unsigned short* g, unsigned short* l) {
  __builtin_amdgcn_global_load_lds(
      (const __attribute__((address_space(1))) unsigned int*)g,
      (__attribute__((address_space(3))) unsigned int*)l, 16, 0, 0);
}

// ---------------- gating + routing ----------------
__global__ __launch_bounds__(256) void gate_route_kernel(
    const float* __restrict__ x, const float* __restrict__ Wg,
    const float* __restrict__ bg,
    int* __restrict__ counts, int* __restrict__ ids, float* __restrict__ wts)
{
  int wave = threadIdx.x >> 6;
  int lane = threadIdx.x & 63;
  int t = blockIdx.x * 4 + wave;
  if (t >= T_TOK) return;

  float acc[NE];
#pragma unroll
  for (int e = 0; e < NE; ++e) acc[e] = 0.f;

  const float* xr = x + (size_t)t * HD;
  for (int h = lane; h < HD; h += 64) {
    float xv = xr[h];
    float4 a = *(const float4*)(Wg + (size_t)h * NE);
    float4 b = *(const float4*)(Wg + (size_t)h * NE + 4);
    acc[0] = fmaf(xv, a.x, acc[0]); acc[1] = fmaf(xv, a.y, acc[1]);
    acc[2] = fmaf(xv, a.z, acc[2]); acc[3] = fmaf(xv, a.w, acc[3]);
    acc[4] = fmaf(xv, b.x, acc[4]); acc[5] = fmaf(xv, b.y, acc[5]);
    acc[6] = fmaf(xv, b.z, acc[6]); acc[7] = fmaf(xv, b.w, acc[7]);
  }
#pragma unroll
  for (int off = 32; off > 0; off >>= 1) {
#pragma unroll
    for (int e = 0; e < NE; ++e) acc[e] += __shfl_xor(acc[e], off);
  }
  if (lane == 0) {
    float lg[NE];
#pragma unroll
    for (int e = 0; e < NE; ++e) lg[e] = acc[e] + bg[e];
    int i1 = 0;
#pragma unroll
    for (int e = 1; e < NE; ++e) if (lg[e] > lg[i1]) i1 = e;
    int i2 = (i1 == 0) ? 1 : 0;
#pragma unroll
    for (int e = 0; e < NE; ++e) if (e != i1 && lg[e] > lg[i2]) i2 = e;
    float p2 = expf(lg[i2] - lg[i1]);
    float s  = 1.f + p2;
    float w1 = 1.f / s;
    float w2 = p2 / s;
    int s1 = atomicAdd(&counts[i1], 1);
    ids[i1 * T_TOK + s1] = t; wts[i1 * T_TOK + s1] = w1;
    int s2 = atomicAdd(&counts[i2], 1);
    ids[i2 * T_TOK + s2] = t; wts[i2 * T_TOK + s2] = w2;
  }
}

// ---------------- prefix offsets (128-aligned) ----------------
__global__ void offs_kernel(const int* __restrict__ counts, int* __restrict__ offs) {
  if (threadIdx.x == 0) {
    int o = 0;
#pragma unroll
    for (int e = 0; e < NE; ++e) { offs[e] = o; o += (counts[e] + 127) & ~127; }
  }
}

// ---------------- weight transpose + bf16 convert ----------------
// in: [E][R][C] fp32 -> out: [E][C][R] bf16
__global__ __launch_bounds__(256) void transpose_cvt_kernel(
    const float* __restrict__ in, unsigned short* __restrict__ out,
    int R, int C)
{
  __shared__ float tile[64][69];
  const int z  = blockIdx.z;
  const int r0 = blockIdx.y * 64, c0 = blockIdx.x * 64;
  const int t  = threadIdx.x;
  const float* ip = in + ((size_t)z * R + r0) * C + c0;
  int tr = t >> 4, tc = (t & 15) * 4;
#pragma unroll
  for (int j = 0; j < 4; ++j) {
    float4 v = *(const float4*)(ip + (size_t)(tr + j * 16) * C + tc);
    float* tp = &tile[tr + j * 16][tc];
    tp[0] = v.x; tp[1] = v.y; tp[2] = v.z; tp[3] = v.w;
  }
  __syncthreads();
  unsigned short* op = out + ((size_t)z * C + c0) * R + r0;
  int oc = t >> 4, orr = (t & 15) * 4;
#pragma unroll
  for (int j = 0; j < 4; ++j) {
    int c = oc + j * 16;
    ushort4 w;
    w.x = f2bf(tile[orr + 0][c]);
    w.y = f2bf(tile[orr + 1][c]);
    w.z = f2bf(tile[orr + 2][c]);
    w.w = f2bf(tile[orr + 3][c]);
    *(ushort4*)(op + (size_t)c * R + orr) = w;
  }
}

// ---------------- gather x rows into expert-sorted bf16 array ----------------
__global__ __launch_bounds__(256) void gather_cvt_kernel(
    const float* __restrict__ x, const int* __restrict__ counts,
    const int* __restrict__ offs, const int* __restrict__ ids,
    unsigned short* __restrict__ Xg)
{
  const int e  = blockIdx.x & 7;
  const int rb = blockIdx.x >> 3;
  const int cnt = counts[e];
  if (rb * 128 >= cnt) return;
  const int base = offs[e] + rb * 128;
  const int tid = threadIdx.x;
#pragma unroll 4
  for (int r = 0; r < 128; ++r) {
    int i = rb * 128 + r;
    unsigned short* orow = Xg + (size_t)(base + r) * HD + tid * 4;
    if (i < cnt) {
      const float* xr = x + (size_t)ids[e * T_TOK + i] * HD + tid * 4;
      float4 v = *(const float4*)xr;
      ushort4 u;
      u.x = f2bf(v.x); u.y = f2bf(v.y); u.z = f2bf(v.z); u.w = f2bf(v.w);
      *(ushort4*)orow = u;
    } else {
      *(ushort4*)orow = (ushort4){0, 0, 0, 0};
    }
  }
}

// ---------------- grouped pair-GEMM (m97-style 128^2 tile, BK=64) ----------------
// A: [pairRows][KD] bf16 (expert-sorted, 128-padded). BT: [E][ND][KD] bf16.
// G1M: Hout[p][col] = relu(A@B^T + bias)   (bias=b1, ND=FFD)
// else: out[tok][col] += wt * (A@B^T + bias) (bias=b2, ND=HD), scatter by ids.
template<int KD, int ND, bool G1M>
__global__ __launch_bounds__(256) void pair_gemm_kernel(
    const unsigned short* __restrict__ A,
    const unsigned short* __restrict__ BT,
    const float* __restrict__ bias,
    const int* __restrict__ counts, const int* __restrict__ offs,
    const int* __restrict__ ids, const float* __restrict__ wts,
    unsigned short* __restrict__ Hout, float* __restrict__ out)
{
  const int bid = blockIdx.x;
  const int e   = bid & 7;          // XCD-pinned expert
  const int q   = bid >> 3;
  const int rt  = q & 31;           // row tile (inner -> B panel stays hot in L2)
  const int ct  = q >> 5;           // col tile
  const int cnt = counts[e];
  if (rt * 128 >= cnt) return;
  const int row0 = offs[e] + rt * 128;

  __shared__ __align__(16) unsigned short As[128 * 64];
  __shared__ __align__(16) unsigned short Bs[128 * 64];

  const int tid  = threadIdx.x;
  const int w    = tid >> 6;
  const int lane = tid & 63;
  const int g    = lane >> 4;     // k-group 0..3
  const int rA   = lane & 15;     // row/col within fragment
  const int RM   = (w >> 1) * 64; // wave quadrant
  const int CN   = (w & 1) * 64;

  const unsigned short* Abase = A + (size_t)row0 * KD;
  const unsigned short* Bbase = BT + ((size_t)e * ND + (size_t)ct * 128) * KD;

  const int srow   = lane >> 3;        // staging: row within 8-row group
  const int schunk = (lane & 7) * 8;   // 16B chunk -> element offset

  f32x4 acc[4][4];
#pragma unroll
  for (int mf = 0; mf < 4; ++mf)
#pragma unroll
    for (int nf = 0; nf < 4; ++nf)
      acc[mf][nf] = (f32x4){0.f, 0.f, 0.f, 0.f};

  for (int kc = 0; kc < KD; kc += 64) {
    __syncthreads();
#pragma unroll
    for (int j = 0; j < 4; ++j) {
      const int rg = (w * 4 + j) * 8;  // 8-row group staged by this instr
      gload_lds16(Abase + (size_t)(rg + srow) * KD + kc + schunk, &As[rg * 64]);
      gload_lds16(Bbase + (size_t)(rg + srow) * KD + kc + schunk, &Bs[rg * 64]);
    }
    __syncthreads();

#pragma unroll
    for (int ks = 0; ks < 2; ++ks) {
      short8 af[4], bf[4];
#pragma unroll
      for (int mf = 0; mf < 4; ++mf)
        af[mf] = *(const short8*)&As[(RM + mf * 16 + rA) * 64 + ks * 32 + g * 8];
#pragma unroll
      for (int nf = 0; nf < 4; ++nf)
        bf[nf] = *(const short8*)&Bs[(CN + nf * 16 + rA) * 64 + ks * 32 + g * 8];
#pragma unroll
      for (int mf = 0; mf < 4; ++mf)
#pragma unroll
        for (int nf = 0; nf < 4; ++nf)
          acc[mf][nf] = __builtin_amdgcn_mfma_f32_16x16x32_bf16(
              af[mf], bf[nf], acc[mf][nf], 0, 0, 0);
    }
  }

  // ---- epilogue ----
  float bv[4];
#pragma unroll
  for (int nf = 0; nf < 4; ++nf)
    bv[nf] = bias[e * ND + ct * 128 + CN + nf * 16 + rA];

  if constexpr (G1M) {
#pragma unroll
    for (int mf = 0; mf < 4; ++mf)
#pragma unroll
      for (int r = 0; r < 4; ++r) {
        const int lrow = RM + mf * 16 + g * 4 + r;
        unsigned short* hrow = Hout + (size_t)(row0 + lrow) * FFD + ct * 128 + CN + rA;
#pragma unroll
        for (int nf = 0; nf < 4; ++nf)
          hrow[nf * 16] = f2bf(fmaxf(acc[mf][nf][r] + bv[nf], 0.f));
      }
  } else {
#pragma unroll
    for (int mf = 0; mf < 4; ++mf)
#pragma unroll
      for (int r = 0; r < 4; ++r) {
        const int lrow = RM + mf * 16 + g * 4 + r;
        const int i = rt * 128 + lrow;
        if (i >= cnt) continue;
        const int tok = ids[e * T_TOK + i];
        const float wt = wts[e * T_TOK + i];
        float* orow = out + (size_t)tok * HD + ct * 128 + CN + rA;
#pragma unroll
        for (int nf = 0; nf < 4; ++nf)
          atomicAdd(&orow[nf * 16], wt * (acc[mf][nf][r] + bv[nf]));
      }
  }
}

// ---------------- round-2 fused MFMA kernel (fallback if ws too small) ----------------
__global__ __launch_bounds__(NTH_F, 2) void moe_mlp_mfma_kernel(
    const float* __restrict__ x,
    const unsigned short* __restrict__ W1T,
    const unsigned short* __restrict__ W2T,
    const float* __restrict__ b1, const float* __restrict__ b2,
    const int* __restrict__ counts, const int* __restrict__ ids,
    const float* __restrict__ wts, float* __restrict__ out)
{
  const int bid  = blockIdx.x;
  const int e    = bid & 7;
  const int tile = bid >> 3;
  const int cnt  = counts[e];
  const int t0   = tile * 32;
  if (t0 >= cnt) return;

  __shared__ unsigned short xs[32 * HD];
  __shared__ unsigned short hs[32 * 512];
  __shared__ int   rows[32];
  __shared__ float tww[32];

  const int tid  = threadIdx.x;
  const int w    = tid >> 6;
  const int lane = tid & 63;
  const int g    = lane >> 4;
  const int rA   = lane & 15;

  if (tid < 32) {
    int idx = t0 + tid;
    rows[tid] = (idx < cnt) ? ids[e * T_TOK + idx] : -1;
    tww[tid]  = (idx < cnt) ? wts[e * T_TOK + idx] : 0.f;
  }
  __syncthreads();

#pragma unroll
  for (int it = 0; it < 8; ++it) {
    int c   = it * NTH_F + tid;
    int row = c >> 7;
    int ck  = c & 127;
    int sck = ck ^ (row & 7);
    short8 sv;
    int rsrc = rows[row];
    if (rsrc >= 0) {
      const float* xp = x + (size_t)rsrc * HD + ck * 8;
      float4 lo = *(const float4*)xp;
      float4 hi = *(const float4*)(xp + 4);
      sv[0] = (short)f2bf(lo.x); sv[1] = (short)f2bf(lo.y);
      sv[2] = (short)f2bf(lo.z); sv[3] = (short)f2bf(lo.w);
      sv[4] = (short)f2bf(hi.x); sv[5] = (short)f2bf(hi.y);
      sv[6] = (short)f2bf(hi.z); sv[7] = (short)f2bf(hi.w);
    } else {
      sv = (short8)0;
    }
    *(short8*)&xs[row * HD + (sck << 3)] = sv;
  }
  __syncthreads();

  f32x4 acc2[2][8];
#pragma unroll
  for (int mf = 0; mf < 2; ++mf)
#pragma unroll
    for (int nf = 0; nf < 8; ++nf)
      acc2[mf][nf] = (f32x4){0.f, 0.f, 0.f, 0.f};

  const unsigned short* W1e = W1T + (size_t)e * FFD * HD;
  const unsigned short* W2e = W2T + (size_t)e * HD * FFD;
  const int sw = rA & 7;

  for (int fc = 0; fc < FFD; fc += 512) {
    f32x4 acc1[2][4];
#pragma unroll
    for (int mf = 0; mf < 2; ++mf)
#pragma unroll
      for (int nf = 0; nf < 4; ++nf)
        acc1[mf][nf] = (f32x4){0.f, 0.f, 0.f, 0.f};

    const unsigned short* bbase = W1e + (size_t)(fc + w * 64 + rA) * HD + 8 * g;
    for (int k0 = 0; k0 < HD; k0 += 32) {
      int ckA = (k0 >> 3) + g;
      int sa  = ((ckA ^ sw) << 3);
      short8 a0 = *(const short8*)&xs[rA * HD + sa];
      short8 a1 = *(const short8*)&xs[(16 + rA) * HD + sa];
      short8 b0 = *(const short8*)(bbase + k0);
      short8 b1f = *(const short8*)(bbase + 16 * HD + k0);
      short8 b2f = *(const short8*)(bbase + 32 * HD + k0);
      short8 b3f = *(const short8*)(bbase + 48 * HD + k0);
      acc1[0][0] = __builtin_amdgcn_mfma_f32_16x16x32_bf16(a0, b0,  acc1[0][0], 0, 0, 0);
      acc1[1][0] = __builtin_amdgcn_mfma_f32_16x16x32_bf16(a1, b0,  acc1[1][0], 0, 0, 0);
      acc1[0][1] = __builtin_amdgcn_mfma_f32_16x16x32_bf16(a0, b1f, acc1[0][1], 0, 0, 0);
      acc1[1][1] = __builtin_amdgcn_mfma_f32_16x16x32_bf16(a1, b1f, acc1[1][1], 0, 0, 0);
      acc1[0][2] = __builtin_amdgcn_mfma_f32_16x16x32_bf16(a0, b2f, acc1[0][2], 0, 0, 0);
      acc1[1][2] = __builtin_amdgcn_mfma_f32_16x16x32_bf16(a1, b2f, acc1[1][2], 0, 0, 0);
      acc1[0][3] = __builtin_amdgcn_mfma_f32_16x16x32_bf16(a0, b3f, acc1[0][3], 0, 0, 0);
      acc1[1][3] = __builtin_amdgcn_mfma_f32_16x16x32_bf16(a1, b3f, acc1[1][3], 0, 0, 0);
    }

    __syncthreads();
    float b1v[4];
#pragma unroll
    for (int nf = 0; nf < 4; ++nf)
      b1v[nf] = b1[e * FFD + fc + w * 64 + nf * 16 + rA];
#pragma unroll
    for (int mf = 0; mf < 2; ++mf)
#pragma unroll
      for (int nf = 0; nf < 4; ++nf)
#pragma unroll
        for (int r = 0; r < 4; ++r) {
          int row = mf * 16 + g * 4 + r;
          int col = w * 64 + nf * 16 + rA;
          float hv = fmaxf(acc1[mf][nf][r] + b1v[nf], 0.f);
          int ck = col >> 3;
          hs[row * 512 + ((ck ^ (row & 7)) << 3) + (col & 7)] = f2bf(hv);
        }
    __syncthreads();

    const unsigned short* b2base = W2e + (size_t)(w * 128 + rA) * FFD + fc + 8 * g;
    for (int k0 = 0; k0 < 512; k0 += 32) {
      int ckA = (k0 >> 3) + g;
      int sa  = ((ckA ^ sw) << 3);
      short8 a0 = *(const short8*)&hs[rA * 512 + sa];
      short8 a1 = *(const short8*)&hs[(16 + rA) * 512 + sa];
#pragma unroll
      for (int nf = 0; nf < 8; ++nf) {
        short8 bv = *(const short8*)(b2base + (size_t)nf * 16 * FFD + k0);
        acc2[0][nf] = __builtin_amdgcn_mfma_f32_16x16x32_bf16(a0, bv, acc2[0][nf], 0, 0, 0);
        acc2[1][nf] = __builtin_amdgcn_mfma_f32_16x16x32_bf16(a1, bv, acc2[1][nf], 0, 0, 0);
      }
    }
  }

#pragma unroll
  for (int mf = 0; mf < 2; ++mf)
#pragma unroll
    for (int nf = 0; nf < 8; ++nf) {
      int col = w * 128 + nf * 16 + rA;
      float b2v = b2[e * HD + col];
#pragma unroll
      for (int r = 0; r < 4; ++r) {
        int row = mf * 16 + g * 4 + r;
        int tr = rows[row];
        if (tr < 0) continue;
        atomicAdd(&out[(size_t)tr * HD + col], tww[row] * (acc2[mf][nf][r] + b2v));
      }
    }
}

extern "C" void kernel_launch(void* const* d_in, const int* in_sizes, int n_in,
                              void* d_out, int out_size, void* d_ws, size_t ws_size,
                              hipStream_t stream) {
  const float* x  = (const float*)d_in[0];
  const float* Wg = (const float*)d_in[1];
  const float* bg = (const float*)d_in[2];
  const float* W1 = (const float*)d_in[3];
  const float* b1 = (const float*)d_in[4];
  const float* W2 = (const float*)d_in[5];
  const float* b2 = (const float*)d_in[6];
  float* out = (float*)d_out;

  // ws layout:
  // [counts 512B][offs 512B][ids 128KB][wts 128KB][W1T 32MB][W2T 32MB][Xg 18.9MB][H 37.7MB]
  const size_t OFF_IDS = 1024;
  const size_t OFF_WTS = OFF_IDS + (size_t)T_TOK * NE * 4;
  const size_t OFF_W1T = OFF_WTS + (size_t)T_TOK * NE * 4;     // 263168
  const size_t OFF_W2T = OFF_W1T + (size_t)NE * HD * FFD * 2;
  const size_t OFF_XG  = OFF_W2T + (size_t)NE * HD * FFD * 2;
  const size_t OFF_H   = OFF_XG + (size_t)9216 * HD * 2;
  const size_t REQ     = OFF_H + (size_t)9216 * FFD * 2;       // ~118.3 MB
  const size_t REQ_FB  = OFF_XG;                                // round-2 path (~64.3 MB)

  int*   counts = (int*)d_ws;
  int*   offs   = (int*)((char*)d_ws + 512);
  int*   ids    = (int*)((char*)d_ws + OFF_IDS);
  float* wts    = (float*)((char*)d_ws + OFF_WTS);

  hipMemsetAsync(counts, 0, 1024, stream);
  hipMemsetAsync(d_out, 0, (size_t)out_size * sizeof(float), stream);

  gate_route_kernel<<<T_TOK / 4, 256, 0, stream>>>(x, Wg, bg, counts, ids, wts);

  if (ws_size >= REQ) {
    unsigned short* W1T = (unsigned short*)((char*)d_ws + OFF_W1T);
    unsigned short* W2T = (unsigned short*)((char*)d_ws + OFF_W2T);
    unsigned short* Xg  = (unsigned short*)((char*)d_ws + OFF_XG);
    unsigned short* H   = (unsigned short*)((char*)d_ws + OFF_H);

    offs_kernel<<<1, 64, 0, stream>>>(counts, offs);
    transpose_cvt_kernel<<<dim3(FFD / 64, HD / 64, NE), 256, 0, stream>>>(W1, W1T, HD, FFD);
    transpose_cvt_kernel<<<dim3(HD / 64, FFD / 64, NE), 256, 0, stream>>>(W2, W2T, FFD, HD);
    gather_cvt_kernel<<<NE * 32, 256, 0, stream>>>(x, counts, offs, ids, Xg);

    pair_gemm_kernel<HD, FFD, true><<<NE * 32 * (FFD / 128), 256, 0, stream>>>(
        Xg, W1T, b1, counts, offs, ids, wts, H, nullptr);
    pair_gemm_kernel<FFD, HD, false><<<NE * 32 * (HD / 128), 256, 0, stream>>>(
        H, W2T, b2, counts, offs, ids, wts, nullptr, out);
  } else if (ws_size >= REQ_FB) {
    unsigned short* W1T = (unsigned short*)((char*)d_ws + OFF_W1T);
    unsigned short* W2T = (unsigned short*)((char*)d_ws + OFF_W2T);
    transpose_cvt_kernel<<<dim3(FFD / 64, HD / 64, NE), 256, 0, stream>>>(W1, W1T, HD, FFD);
    transpose_cvt_kernel<<<dim3(HD / 64, FFD / 64, NE), 256, 0, stream>>>(W2, W2T, FFD, HD);
    moe_mlp_mfma_kernel<<<(T_TOK / 32) * NE, NTH_F, 0, stream>>>(
        x, W1T, W2T, b1, b2, counts, ids, wts, out);
  }
}